// Round 4
// baseline (226.634 us; speedup 1.0000x reference)
//
#include <hip/hip_runtime.h>
#include <cmath>

// ---------------------------------------------------------------------------
// JPEG compress (YCbCr + 2x2 chroma pool + 8x8 DCT + quantize/round).
//
// Numerics contract (H_C', R3->R4): the harness's np reference is the
// transpiled module run in FLOAT32 end-to-end, and numpy's einsum SOP
// loops are compiled at baseline SIMD (no FMA): every accumulation step is
// mul-then-add, TWO roundings. Evidence: f64 variants fail (r1/r3), f32
// with FMA chains fails (r2), all with absmax exactly 1.0 (pure flips).
// Replicated recipe per output:
//   t_c   = rn(x_c * 255)
//   y     = rn(rn(0.299 tR) + rn(0.587 tG)) ... sequential c-chain, mul+add
//   cb/cr = same chain + 128 (shift), per pixel
//   pool  = ((p00+p01)+p10)+p11 then *0.25 (exact)
//   X     = rn(v - 128)
//   dct_i = 64-step chain over j=(x,y) row-major from 0: a = rn(a + rn(X_j*T_ij))
//   outv  = rintf( rn( rn(sc_i * dct_i) / q_i ) )     (round half-to-even)
// Constants f32-rounded from f64 (module .astype(np.float32)); all ops via
// __f*_rn builtins so LLVM cannot re-fuse into FMA.
//
// Structure: lane-owns-block. 64-lane wave = 64 blocks; X[64] f32 per lane
// in VGPRs; DCT table index wave-uniform -> scalar loads; no LDS.
// ---------------------------------------------------------------------------

namespace jc {

constexpr double c1 = 0.98078528040323044912618223613424;  // cos(1*pi/16)
constexpr double c2 = 0.92387953251128675612818318939679;  // cos(2*pi/16)
constexpr double c3 = 0.83146961230254523707878837761791;  // cos(3*pi/16)
constexpr double c4 = 0.70710678118654752440084436210485;  // cos(4*pi/16)
constexpr double c5 = 0.55557023301960222474283081394853;  // cos(5*pi/16)
constexpr double c6 = 0.38268343236508977172845998403040;  // cos(6*pi/16)
constexpr double c7 = 0.19509032201612826784828486847702;  // cos(7*pi/16)
// f64 value of numpy's 1.0/np.sqrt(2.0) (0x3FE6A09E667F3BCC):
constexpr double alpha0 = 0.70710678118654746171979706919384;

struct Tab {
  float t[4096];   // t[i*64+j] = f32(CX[x][u]*CX[y][v]), i=(u,v), j=(x,y)
  float sc[64];    // f32(f64(alpha_u*alpha_v)*0.25)
  float yq[64];    // Y quant table (exact small ints)
  float cq[64];    // C quant table
  constexpr Tab() : t(), sc(), yq(), cq() {
    const double CX[8][8] = {  // CX[x][u] = cos((2x+1)u*pi/16)
      {1.0,  c1,  c2,  c3,  c4,  c5,  c6,  c7},
      {1.0,  c3,  c6, -c7, -c4, -c1, -c2, -c5},
      {1.0,  c5, -c6, -c1, -c4,  c7,  c2,  c3},
      {1.0,  c7, -c2, -c5,  c4,  c3, -c6, -c1},
      {1.0, -c7, -c2,  c5,  c4, -c3, -c6,  c1},
      {1.0, -c5, -c6,  c1, -c4, -c7,  c2, -c3},
      {1.0, -c3,  c6,  c7, -c4,  c1, -c2,  c5},
      {1.0, -c1,  c2, -c3,  c4, -c5,  c6, -c7}};
    for (int i = 0; i < 64; ++i) {
      const int u = i >> 3, v = i & 7;
      for (int j = 0; j < 64; ++j) {
        const int x = j >> 3, y = j & 7;
        t[i * 64 + j] = (float)(CX[x][u] * CX[y][v]);
      }
      const double au = (u == 0) ? alpha0 : 1.0;
      const double av = (v == 0) ? alpha0 : 1.0;
      sc[i] = (float)((au * av) * 0.25);
    }
    const int YT[64] = {
      16, 11, 10, 16, 24, 40, 51, 61,
      12, 12, 14, 19, 26, 58, 60, 55,
      14, 13, 16, 24, 40, 57, 69, 56,
      14, 17, 22, 29, 51, 87, 80, 62,
      18, 22, 37, 56, 68, 109, 103, 77,
      24, 35, 55, 64, 81, 104, 113, 92,
      49, 64, 78, 87, 103, 121, 120, 101,
      72, 92, 95, 98, 112, 100, 103, 99};
    const int CT[64] = {
      17, 18, 24, 47, 99, 99, 99, 99,
      18, 21, 26, 66, 99, 99, 99, 99,
      24, 26, 56, 99, 99, 99, 99, 99,
      47, 66, 99, 99, 99, 99, 99, 99,
      99, 99, 99, 99, 99, 99, 99, 99,
      99, 99, 99, 99, 99, 99, 99, 99,
      99, 99, 99, 99, 99, 99, 99, 99,
      99, 99, 99, 99, 99, 99, 99, 99};
    for (int i = 0; i < 64; ++i) {
      yq[i] = (float)YT[i];
      cq[i] = (float)CT[i];
    }
  }
};

__device__ constexpr Tab TT;

}  // namespace jc

// mul+add, two roundings, no fusion (baseline-SIMD numpy semantics)
__device__ __forceinline__ float madd(float a, float b, float acc) {
  return __fadd_rn(acc, __fmul_rn(a, b));
}

// Per-pixel luma: t = rn(x*255); chain over c = R,G,B, mul+add per step
__device__ __forceinline__ float ylum(float R, float G, float B) {
  const float tR = __fmul_rn(R, 255.0f);
  const float tG = __fmul_rn(G, 255.0f);
  const float tB = __fmul_rn(B, 255.0f);
  float a = __fmul_rn(tR, 0.299f);   // first step: 0 + rn(tR*k) == rn(tR*k)
  a = madd(tG, 0.587f, a);
  a = madd(tB, 0.114f, a);
  return a;
}

// Per-pixel chroma (pre-pool, includes +128 shift like the reference)
__device__ __forceinline__ float chro(float R, float G, float B,
                                      float kR, float kG, float kB) {
  const float tR = __fmul_rn(R, 255.0f);
  const float tG = __fmul_rn(G, 255.0f);
  const float tB = __fmul_rn(B, 255.0f);
  float a = __fmul_rn(tR, kR);
  a = madd(tG, kG, a);
  a = madd(tB, kB, a);
  return __fadd_rn(a, 128.0f);
}

// grid: 3072 blocks x 64 threads. blocks 0..2047: Y (64x64-px region each,
// lane = one 8x8 block). blocks 2048..3071: chroma (128x64-px region, lanes
// 0-31 Cb blocks, lanes 32-63 Cr blocks; each lane owns a 16x16-px patch).
__global__ __launch_bounds__(64) void jpeg_kernel(const float* __restrict__ img,
                                                  float* __restrict__ out) {
  const int wid = blockIdx.x;
  const int ln = threadIdx.x;

  float X[64];
  float* outp;
  const float* qt;

  if (wid < 2048) {
    // ---------------- Y wave ----------------
    const int b = wid >> 6;
    const int r = wid & 63;                    // region within image (8x8 grid)
    const int gby = (r >> 3) * 8 + (ln >> 3);  // global block row 0..63
    const int gbx = (r & 7) * 8 + (ln & 7);    // global block col 0..63
    const float* rp = img + (size_t)b * 786432 + gby * 4096 + gbx * 8;
#pragma unroll
    for (int x = 0; x < 8; ++x) {
      const float4 r0 = *(const float4*)(rp + x * 512);
      const float4 r1 = *(const float4*)(rp + x * 512 + 4);
      const float4 g0 = *(const float4*)(rp + 262144 + x * 512);
      const float4 g1 = *(const float4*)(rp + 262144 + x * 512 + 4);
      const float4 b0 = *(const float4*)(rp + 524288 + x * 512);
      const float4 b1 = *(const float4*)(rp + 524288 + x * 512 + 4);
      X[x * 8 + 0] = __fsub_rn(ylum(r0.x, g0.x, b0.x), 128.0f);
      X[x * 8 + 1] = __fsub_rn(ylum(r0.y, g0.y, b0.y), 128.0f);
      X[x * 8 + 2] = __fsub_rn(ylum(r0.z, g0.z, b0.z), 128.0f);
      X[x * 8 + 3] = __fsub_rn(ylum(r0.w, g0.w, b0.w), 128.0f);
      X[x * 8 + 4] = __fsub_rn(ylum(r1.x, g1.x, b1.x), 128.0f);
      X[x * 8 + 5] = __fsub_rn(ylum(r1.y, g1.y, b1.y), 128.0f);
      X[x * 8 + 6] = __fsub_rn(ylum(r1.z, g1.z, b1.z), 128.0f);
      X[x * 8 + 7] = __fsub_rn(ylum(r1.w, g1.w, b1.w), 128.0f);
    }
    outp = out + ((size_t)(b * 4096 + gby * 64 + gbx) << 6);
    qt = jc::TT.yq;
  } else {
    // ---------------- chroma wave ----------------
    const int cw = wid - 2048;
    const int b = cw >> 5;
    const int reg = cw & 31;        // chroma region (8 rows x 4 cols)
    const int typ = ln >> 5;        // 0 = Cb, 1 = Cr
    const int s = ln & 31;
    const int cby = (reg >> 2) * 4 + (s >> 3);  // chroma block row 0..31
    const int cbx = (reg & 3) * 8 + (s & 7);    // chroma block col 0..31
    const float* base = img + (size_t)b * 786432 + cby * 8192 + cbx * 16;
    const float kR = typ ? 0.5f       : -0.168736f;
    const float kG = typ ? -0.418688f : -0.331264f;
    const float kB = typ ? -0.081312f : 0.5f;
#pragma unroll
    for (int pr = 0; pr < 8; ++pr) {
      float px[3][2][16];  // channel, row-in-pair, col (unrolled -> registers)
#pragma unroll
      for (int c = 0; c < 3; ++c) {
#pragma unroll
        for (int rr = 0; rr < 2; ++rr) {
          const float* p0 = base + c * 262144 + pr * 1024 + rr * 512;
#pragma unroll
          for (int q = 0; q < 4; ++q) {
            const float4 v = *(const float4*)(p0 + q * 4);
            px[c][rr][q * 4 + 0] = v.x;
            px[c][rr][q * 4 + 1] = v.y;
            px[c][rr][q * 4 + 2] = v.z;
            px[c][rr][q * 4 + 3] = v.w;
          }
        }
      }
#pragma unroll
      for (int pc = 0; pc < 8; ++pc) {
        const int c0 = 2 * pc, c1 = 2 * pc + 1;
        const float p00 = chro(px[0][0][c0], px[1][0][c0], px[2][0][c0], kR, kG, kB);
        const float p01 = chro(px[0][0][c1], px[1][0][c1], px[2][0][c1], kR, kG, kB);
        const float p10 = chro(px[0][1][c0], px[1][1][c0], px[2][1][c0], kR, kG, kB);
        const float p11 = chro(px[0][1][c1], px[1][1][c1], px[2][1][c1], kR, kG, kB);
        // numpy mean(axis=(2,4)): single-pass memory-order sum, then /4 (exact)
        const float ssum = __fadd_rn(__fadd_rn(__fadd_rn(p00, p01), p10), p11);
        const float m = __fmul_rn(ssum, 0.25f);
        X[pr * 8 + pc] = __fsub_rn(m, 128.0f);
      }
    }
    outp = out + 8388608 + (size_t)typ * 2097152 +
           ((size_t)(b * 1024 + cby * 32 + cbx) << 6);
    qt = jc::TT.cq;
  }

  // ---------------- DCT + quantize (all lanes) ----------------
  for (int i = 0; i < 64; i += 4) {
    const float* tr = jc::TT.t + i * 64;
    float a0 = 0.0f, a1 = 0.0f, a2 = 0.0f, a3 = 0.0f;
#pragma unroll
    for (int j = 0; j < 64; ++j) {
      // np einsum SOP (baseline SIMD, no FMA): out = rn(out + rn(X*t)),
      // sequential j=(x,y) row-major
      a0 = madd(X[j], tr[j], a0);
      a1 = madd(X[j], tr[64 + j], a1);
      a2 = madd(X[j], tr[128 + j], a2);
      a3 = madd(X[j], tr[192 + j], a3);
    }
    float4 stv;
    stv.x = rintf(__fdiv_rn(__fmul_rn(jc::TT.sc[i + 0], a0), qt[i + 0]));
    stv.y = rintf(__fdiv_rn(__fmul_rn(jc::TT.sc[i + 1], a1), qt[i + 1]));
    stv.z = rintf(__fdiv_rn(__fmul_rn(jc::TT.sc[i + 2], a2), qt[i + 2]));
    stv.w = rintf(__fdiv_rn(__fmul_rn(jc::TT.sc[i + 3], a3), qt[i + 3]));
    *(float4*)(outp + i) = stv;
  }
}

extern "C" void kernel_launch(void* const* d_in, const int* in_sizes, int n_in,
                              void* d_out, int out_size, void* d_ws, size_t ws_size,
                              hipStream_t stream) {
  (void)in_sizes; (void)n_in; (void)d_ws; (void)ws_size; (void)out_size;
  const float* img = (const float*)d_in[0];
  float* out = (float*)d_out;
  jpeg_kernel<<<dim3(3072), dim3(64), 0, stream>>>(img, out);
}